// Round 2
// baseline (779.075 us; speedup 1.0000x reference)
//
#include <hip/hip_runtime.h>

#define C_IN 256
#define CR   64      // C / reduction
#define G_   16      // groups
#define GC_  16      // group channels
#define K_   7
#define KK   49
#define PAD_ 3
#define H_   64
#define W_   64
#define HW   4096
#define OO   784     // K*K*G
#define EPSV 1e-5f

// ---------------- prep: transpose w1 (BN-folded), transpose w2, fold b1 ----
__global__ __launch_bounds__(256) void prep_kernel(
    const float* __restrict__ w1, const float* __restrict__ b1,
    const float* __restrict__ gamma, const float* __restrict__ beta,
    const float* __restrict__ mean, const float* __restrict__ var,
    const float* __restrict__ w2,
    float* __restrict__ w1t, float* __restrict__ b1f, float* __restrict__ w2t)
{
  int idx = blockIdx.x * 256 + threadIdx.x;
  if (idx < CR * C_IN) {                       // w1 is [o=64][c=256]
    int o = idx / C_IN, c = idx % C_IN;
    float s = gamma[o] * rsqrtf(var[o] + EPSV);
    w1t[c * CR + o] = w1[idx] * s;
  }
  if (idx < CR) {
    float s = gamma[idx] * rsqrtf(var[idx] + EPSV);
    b1f[idx] = (b1[idx] - mean[idx]) * s + beta[idx];
  }
  if (idx < OO * CR) {                         // w2 is [oo=784][c=64]
    int o = idx / CR, c = idx % CR;
    w2t[c * OO + o] = w2[idx];
  }
}

// ---------------- conv1 (1x1, 256->64) + folded BN + ReLU ----------------
// block: 256 thr = 64 px * 4 j ; each thread computes 16 channels o = j*16+jo
__global__ __launch_bounds__(256) void conv1_kernel(
    const float* __restrict__ x, const float* __restrict__ w1t,  // [c][o] 256x64
    const float* __restrict__ b1f, float* __restrict__ t)
{
  __shared__ float xs[C_IN][64];                    // 64 KB
  const int px  = threadIdx.x & 63;
  const int ju  = __builtin_amdgcn_readfirstlane(threadIdx.x >> 6);
  const int hw0 = blockIdx.x * 64;
  const int b   = blockIdx.y;
  const float* xb = x + ((size_t)b * C_IN) * HW + hw0;

  for (int i = threadIdx.x; i < C_IN * 64; i += 256) {
    int c = i >> 6, p = i & 63;
    xs[c][p] = xb[(size_t)c * HW + p];
  }
  __syncthreads();

  float acc[16];
#pragma unroll
  for (int jo = 0; jo < 16; ++jo) acc[jo] = 0.f;

  for (int c = 0; c < C_IN; ++c) {
    float xv = xs[c][px];
    const float* wrow = w1t + c * CR + ju * 16;     // wave-uniform -> s_load
#pragma unroll
    for (int jo = 0; jo < 16; ++jo)
      acc[jo] = fmaf(xv, wrow[jo], acc[jo]);
  }

#pragma unroll
  for (int jo = 0; jo < 16; ++jo) {
    int o = ju * 16 + jo;
    t[((size_t)b * CR + o) * HW + hw0 + px] = fmaxf(acc[jo] + b1f[o], 0.f);
  }
}

// ---------------- fused conv2 + involution ----------------
// thread = one pixel of one (b, g). Phase 1: generate this pixel's 49 weights
// in registers (w2 operands wave-uniform -> scalar loads). Phase 2: apply to
// the 16 group channels, kk-outer so addr+bounds amortize over gc.
// grid: (HW/256, G, B); wave = one image row (h uniform per wave).
__global__ __launch_bounds__(256) void conv2invol_kernel(
    const float* __restrict__ x, const float* __restrict__ t,
    const float* __restrict__ w2t,  // [c][oo] 64x784
    const float* __restrict__ b2, float* __restrict__ out)
{
  const int hw = blockIdx.x * 256 + threadIdx.x;
  const int g  = blockIdx.y;
  const int b  = blockIdx.z;
  const int h  = hw >> 6, w = hw & 63;

  // ---- phase 1: weight generation ----
  float wreg[KK];
  const float* b2g = b2 + g * KK;                  // uniform
#pragma unroll
  for (int kk = 0; kk < KK; ++kk) wreg[kk] = b2g[kk];

  const float* tb  = t + ((size_t)b * CR) * HW + hw;
  const float* w2g = w2t + g * KK;                 // row stride OO, uniform idx
  for (int c = 0; c < CR; ++c) {
    float xv = tb[(size_t)c * HW];                 // coalesced vector load
#pragma unroll
    for (int kk = 0; kk < KK; ++kk)
      wreg[kk] = fmaf(xv, w2g[c * OO + kk], wreg[kk]);
  }

  // ---- phase 2: apply ----
  float acc[GC_];
#pragma unroll
  for (int gc = 0; gc < GC_; ++gc) acc[gc] = 0.f;

  const float* xb = x + ((size_t)b * C_IN + g * GC_) * HW;
#pragma unroll
  for (int kk = 0; kk < KK; ++kk) {
    const int y  = h + kk / K_ - PAD_;             // wave-uniform validity
    const int xx = w + kk % K_ - PAD_;
    const bool ok = ((unsigned)y < (unsigned)H_) & ((unsigned)xx < (unsigned)W_);
    const float* xp = xb + y * W_ + xx;
    const float wk = wreg[kk];
#pragma unroll
    for (int gc = 0; gc < GC_; ++gc) {
      float xv = ok ? xp[(size_t)gc * HW] : 0.f;
      acc[gc] = fmaf(wk, xv, acc[gc]);
    }
  }

  float* ob = out + ((size_t)b * C_IN + g * GC_) * HW + hw;
#pragma unroll
  for (int gc = 0; gc < GC_; ++gc)
    ob[(size_t)gc * HW] = acc[gc];
}

extern "C" void kernel_launch(void* const* d_in, const int* in_sizes, int n_in,
                              void* d_out, int out_size, void* d_ws, size_t ws_size,
                              hipStream_t stream) {
  const float* x     = (const float*)d_in[0];
  const float* w1    = (const float*)d_in[1];
  const float* b1    = (const float*)d_in[2];
  const float* gamma = (const float*)d_in[3];
  const float* beta  = (const float*)d_in[4];
  const float* mean  = (const float*)d_in[5];
  const float* var   = (const float*)d_in[6];
  const float* w2    = (const float*)d_in[7];
  const float* b2    = (const float*)d_in[8];
  float* out = (float*)d_out;
  const int B = in_sizes[0] / (C_IN * HW);

  // ws layout: [w1t 64KB][b1f][w2t 200KB][t B*1MB]
  char* p = (char*)d_ws;
  float* w1t = (float*)p;  p += ((size_t)CR * C_IN * 4 + 255) & ~(size_t)255;
  float* b1f = (float*)p;  p += ((size_t)CR * 4 + 255) & ~(size_t)255;
  float* w2t = (float*)p;  p += ((size_t)OO * CR * 4 + 255) & ~(size_t)255;
  float* t   = (float*)p;

  prep_kernel<<<dim3((OO * CR + 255) / 256), 256, 0, stream>>>(
      w1, b1, gamma, beta, mean, var, w2, w1t, b1f, w2t);

  conv1_kernel<<<dim3(HW / 64, B), 256, 0, stream>>>(x, w1t, b1f, t);

  conv2invol_kernel<<<dim3(HW / 256, G_, B), 256, 0, stream>>>(x, t, w2t, b2, out);
}

// Round 3
// 189.910 us; speedup vs baseline: 4.1023x; 4.1023x over previous
//
#include <hip/hip_runtime.h>

#define C_IN 256
#define CR   64      // C / reduction
#define G_   16      // groups
#define GC_  16      // group channels
#define K_   7
#define KK   49
#define PAD_ 3
#define H_   64
#define W_   64
#define HW   4096
#define OO   784     // K*K*G
#define EPSV 1e-5f
#define WTAPS 13     // ceil(49/4) taps per wave in phase 1

// ---------------- prep: transpose w1 (BN-folded), transpose w2, fold b1 ----
__global__ __launch_bounds__(256) void prep_kernel(
    const float* __restrict__ w1, const float* __restrict__ b1,
    const float* __restrict__ gamma, const float* __restrict__ beta,
    const float* __restrict__ mean, const float* __restrict__ var,
    const float* __restrict__ w2,
    float* __restrict__ w1t, float* __restrict__ b1f, float* __restrict__ w2t)
{
  int idx = blockIdx.x * 256 + threadIdx.x;
  if (idx < CR * C_IN) {                       // w1 is [o=64][c=256]
    int o = idx / C_IN, c = idx % C_IN;
    float s = gamma[o] * rsqrtf(var[o] + EPSV);
    w1t[c * CR + o] = w1[idx] * s;
  }
  if (idx < CR) {
    float s = gamma[idx] * rsqrtf(var[idx] + EPSV);
    b1f[idx] = (b1[idx] - mean[idx]) * s + beta[idx];
  }
  if (idx < OO * CR) {                         // w2 is [oo=784][c=64]
    int o = idx / CR, c = idx % CR;
    w2t[c * OO + o] = w2[idx];
  }
}

// ---------------- conv1 (1x1, 256->64) + folded BN + ReLU ----------------
// thread = 4 px (float4) x 2 outputs; block 256 thr = 16 px-quads x 16 o-pairs
// covering 64 px x 32 o.  grid: (HW/64, 2, B) -> 2048 waves.
__global__ __launch_bounds__(256) void conv1_kernel(
    const float* __restrict__ x, const float* __restrict__ w1t,  // [c][o] 256x64
    const float* __restrict__ b1f, float* __restrict__ t)
{
  const int quad = threadIdx.x & 15;           // px quad
  const int oi   = threadIdx.x >> 4;           // 0..15
  const int o0   = blockIdx.y * 32 + oi * 2;   // two outputs o0, o0+1
  const int hw0  = blockIdx.x * 64 + quad * 4;
  const int b    = blockIdx.z;

  const float* xb = x + ((size_t)b * C_IN) * HW + hw0;

  float acc0[4] = {0.f, 0.f, 0.f, 0.f};
  float acc1[4] = {0.f, 0.f, 0.f, 0.f};

  for (int c = 0; c < C_IN; ++c) {
    float xv[4];
    *(float4*)xv = *(const float4*)(xb + (size_t)c * HW);
    const float w0v = w1t[c * CR + o0];        // wave-uniform -> s_load
    const float w1v = w1t[c * CR + o0 + 1];
#pragma unroll
    for (int p = 0; p < 4; ++p) {
      acc0[p] = fmaf(xv[p], w0v, acc0[p]);
      acc1[p] = fmaf(xv[p], w1v, acc1[p]);
    }
  }

  const float bb0 = b1f[o0], bb1 = b1f[o0 + 1];
  float r0[4], r1[4];
#pragma unroll
  for (int p = 0; p < 4; ++p) {
    r0[p] = fmaxf(acc0[p] + bb0, 0.f);
    r1[p] = fmaxf(acc1[p] + bb1, 0.f);
  }
  float* tb = t + ((size_t)b * CR) * HW + hw0;
  *(float4*)(tb + (size_t)o0 * HW)       = *(float4*)r0;
  *(float4*)(tb + (size_t)(o0 + 1) * HW) = *(float4*)r1;
}

// ---------------- fused conv2 + involution, weights in LDS ----------------
// block = one image row (64 px) of one (b, g). 256 threads.
// Phase 1: conv2 -> wlds[kk][px]  (4 waves x 13 taps, 13 regs/thread)
// Phase 2: involution: thread = (px-quad, gc), acc[4]; float4 x loads;
//          weights via ds_read_b128 (16 segments x 4-way broadcast).
// grid: (64 rows, G, B)
__global__ __launch_bounds__(256) void conv2invol_kernel(
    const float* __restrict__ x, const float* __restrict__ t,
    const float* __restrict__ w2t,  // [c][oo] 64x784
    const float* __restrict__ b2, float* __restrict__ out)
{
  __shared__ float wlds[KK * 64];              // [kk][px], 12.5 KB
  const int tid = threadIdx.x;
  const int row = blockIdx.x;
  const int g   = blockIdx.y;
  const int b   = blockIdx.z;

  // ---- phase 1: generate this row's 49x64 weights ----
  {
    const int px  = tid & 63;
    const int j   = __builtin_amdgcn_readfirstlane(tid >> 6);
    const int kk0 = j * WTAPS;

    float acc[WTAPS];
#pragma unroll
    for (int i = 0; i < WTAPS; ++i) {
      int kk = kk0 + i;
      acc[i] = (kk < KK) ? b2[g * KK + kk] : 0.f;
    }

    const float* tb  = t + ((size_t)b * CR) * HW + row * W_ + px;
    const float* w2g = w2t + g * KK;
    for (int c = 0; c < CR; ++c) {
      float xv = tb[(size_t)c * HW];
      const int base = c * OO;
#pragma unroll
      for (int i = 0; i < WTAPS; ++i) {
        int kk = kk0 + i; kk = kk < KK ? kk : KK - 1;  // clamp (no OOB)
        acc[i] = fmaf(xv, w2g[base + kk], acc[i]);
      }
    }
#pragma unroll
    for (int i = 0; i < WTAPS; ++i) {
      int kk = kk0 + i;
      if (kk < KK) wlds[kk * 64 + px] = acc[i];
    }
  }
  __syncthreads();

  // ---- phase 2: apply ----
  const int quad = tid & 15;                   // px quad: w0 = quad*4
  const int gc   = tid >> 4;                   // group channel 0..15
  const int w0   = quad * 4;

  float acc4[4] = {0.f, 0.f, 0.f, 0.f};
  const float* xp = x + ((size_t)b * C_IN + g * GC_ + gc) * HW;

#pragma unroll
  for (int kh = 0; kh < K_; ++kh) {
    const int y = row + kh - PAD_;
    if ((unsigned)y < (unsigned)H_) {          // wave-uniform branch
      const float* xr = xp + y * W_;
      float win[12];
      float4 zero4 = {0.f, 0.f, 0.f, 0.f};
      *(float4*)&win[0] = (w0 >= 4)  ? *(const float4*)(xr + w0 - 4) : zero4;
      *(float4*)&win[4] = *(const float4*)(xr + w0);
      *(float4*)&win[8] = (w0 <= 56) ? *(const float4*)(xr + w0 + 4) : zero4;
#pragma unroll
      for (int dw = 0; dw < 7; ++dw) {
        float wv[4];
        *(float4*)wv = *(const float4*)&wlds[(kh * 7 + dw) * 64 + w0];
#pragma unroll
        for (int cc = 0; cc < 4; ++cc)
          acc4[cc] = fmaf(wv[cc], win[cc + dw + 1], acc4[cc]);
      }
    }
  }

  float* ob = out + ((size_t)b * C_IN + g * GC_ + gc) * HW + row * W_ + w0;
  *(float4*)ob = *(float4*)acc4;
}

extern "C" void kernel_launch(void* const* d_in, const int* in_sizes, int n_in,
                              void* d_out, int out_size, void* d_ws, size_t ws_size,
                              hipStream_t stream) {
  const float* x     = (const float*)d_in[0];
  const float* w1    = (const float*)d_in[1];
  const float* b1    = (const float*)d_in[2];
  const float* gamma = (const float*)d_in[3];
  const float* beta  = (const float*)d_in[4];
  const float* mean  = (const float*)d_in[5];
  const float* var   = (const float*)d_in[6];
  const float* w2    = (const float*)d_in[7];
  const float* b2    = (const float*)d_in[8];
  float* out = (float*)d_out;
  const int B = in_sizes[0] / (C_IN * HW);

  // ws layout: [w1t 64KB][b1f][w2t 200KB][t B*1MB]
  char* p = (char*)d_ws;
  float* w1t = (float*)p;  p += ((size_t)CR * C_IN * 4 + 255) & ~(size_t)255;
  float* b1f = (float*)p;  p += ((size_t)CR * 4 + 255) & ~(size_t)255;
  float* w2t = (float*)p;  p += ((size_t)OO * CR * 4 + 511) & ~(size_t)255;
  float* t   = (float*)p;

  prep_kernel<<<dim3((OO * CR + 255) / 256), 256, 0, stream>>>(
      w1, b1, gamma, beta, mean, var, w2, w1t, b1f, w2t);

  conv1_kernel<<<dim3(HW / 64, 2, B), 256, 0, stream>>>(x, w1t, b1f, t);

  conv2invol_kernel<<<dim3(H_, G_, B), 256, 0, stream>>>(x, t, w2t, b2, out);
}

// Round 5
// 180.165 us; speedup vs baseline: 4.3242x; 1.0541x over previous
//
#include <hip/hip_runtime.h>

#define C_IN 256
#define CR   64      // C / reduction
#define G_   16      // groups
#define GC_  16      // group channels
#define K_   7
#define KK   49
#define PAD_ 3
#define H_   64
#define W_   64
#define HW   4096
#define OO   784     // K^2 * G
#define EPSV 1e-5f
#define WTAPS 13     // taps per wave in phase 1 (4 waves cover 49 with clamp)

// ---------------- prep: transpose w1 (BN-folded), transpose w2, fold b1 ----
__global__ __launch_bounds__(256) void prep_kernel(
    const float* __restrict__ w1, const float* __restrict__ b1,
    const float* __restrict__ gamma, const float* __restrict__ beta,
    const float* __restrict__ mean, const float* __restrict__ var,
    const float* __restrict__ w2,
    float* __restrict__ w1t, float* __restrict__ b1f, float* __restrict__ w2t)
{
  int idx = blockIdx.x * 256 + threadIdx.x;
  if (idx < CR * C_IN) {                       // w1 is [o=64][c=256]
    int o = idx / C_IN, c = idx % C_IN;
    float s = gamma[o] * rsqrtf(var[o] + EPSV);
    w1t[c * CR + o] = w1[idx] * s;
  }
  if (idx < CR) {
    float s = gamma[idx] * rsqrtf(var[idx] + EPSV);
    b1f[idx] = (b1[idx] - mean[idx]) * s + beta[idx];
  }
  if (idx < OO * CR) {                         // w2 is [oo=784][c=64]
    int o = idx / CR, c = idx % CR;
    w2t[c * OO + o] = w2[idx];
  }
}

// ---------------- conv1 (1x1, 256->64) + folded BN + ReLU ----------------
// block = 1024 thr = 16 waves; lane = px (64-px row), wave j -> o quad 4j..4j+3.
// Weights wave-uniform (s_load_dwordx4); x loads 256B coalesced, L1-shared by
// all 16 waves. Output t is px-major: t[b][hw][c].
// grid: (HW/64, B) = 256 blocks -> exactly 1 block/CU.
__global__ __launch_bounds__(1024) void conv1_kernel(
    const float* __restrict__ x, const float* __restrict__ w1t,  // [c][o] 256x64
    const float* __restrict__ b1f, float* __restrict__ t)
{
  const int px = threadIdx.x & 63;
  const int j  = __builtin_amdgcn_readfirstlane(threadIdx.x >> 6);  // 0..15
  const int o0 = j * 4;
  const int hw0 = blockIdx.x * 64;
  const int b   = blockIdx.y;

  const float* xb = x + ((size_t)b * C_IN) * HW + hw0 + px;

  float acc[4] = {0.f, 0.f, 0.f, 0.f};
#pragma unroll 8
  for (int c = 0; c < C_IN; ++c) {
    float xv = xb[(size_t)c * HW];
    float4 wv = *(const float4*)(w1t + c * CR + o0);   // uniform -> s_load x4
    acc[0] = fmaf(xv, wv.x, acc[0]);
    acc[1] = fmaf(xv, wv.y, acc[1]);
    acc[2] = fmaf(xv, wv.z, acc[2]);
    acc[3] = fmaf(xv, wv.w, acc[3]);
  }

  float4 bb = *(const float4*)(b1f + o0);
  float r[4];
  r[0] = fmaxf(acc[0] + bb.x, 0.f);
  r[1] = fmaxf(acc[1] + bb.y, 0.f);
  r[2] = fmaxf(acc[2] + bb.z, 0.f);
  r[3] = fmaxf(acc[3] + bb.w, 0.f);
  // px-major store: t[(b*HW + hw)*CR + o0 .. +3]
  *(float4*)(t + ((size_t)(b * HW + hw0 + px)) * CR + o0) = *(float4*)r;
}

// ---------------- fused conv2 + involution, weights in LDS ----------------
// 1-D grid 4096, XCD-swizzled decode: all 16 g-blocks of one (b,row) land on
// the same XCD so the t row (16 KB) is L2-resident after first use.
// Phase 1: thread (px, wave j) computes 13 taps; t loads = 16 independent b128
// (px-major t). Phase 2: thread = (px-quad, gc), acc[4], float4 x loads,
// weights via ds_read_b128 broadcast.
__global__ __launch_bounds__(256) void conv2invol_kernel(
    const float* __restrict__ x, const float* __restrict__ t,
    const float* __restrict__ w2t,  // [c][oo] 64x784
    const float* __restrict__ b2, float* __restrict__ out)
{
  __shared__ float wlds[KK * 64];              // [kk][px], 12.5 KB
  const int tid = threadIdx.x;

  // swizzle decode: dispatch round-robins XCD = L % 8
  const int L     = blockIdx.x;
  const int xcd   = L & 7;
  const int chunk = L >> 3;                    // 0..511
  const int g     = chunk >> 5;                // 0..15
  const int pr    = (chunk & 31) + (xcd << 5); // 0..255 = (b,row)
  const int b     = pr >> 6;
  const int row   = pr & 63;

  // ---- phase 1: generate this row's 49x64 weights ----
  {
    const int px  = tid & 63;
    const int j   = __builtin_amdgcn_readfirstlane(tid >> 6);
    const int kk0 = j * WTAPS;

    float acc[WTAPS];
#pragma unroll
    for (int i = 0; i < WTAPS; ++i) {
      int kk = kk0 + i; kk = kk < KK ? kk : KK - 1;
      acc[i] = b2[g * KK + kk];
    }

    const float* tb = t + ((size_t)(b * HW + row * W_ + px)) * CR;
#pragma unroll 4
    for (int c0 = 0; c0 < 16; ++c0) {
      float xv[4];
      *(float4*)xv = *(const float4*)(tb + 4 * c0);
#pragma unroll
      for (int cc = 0; cc < 4; ++cc) {
        const float* wr = w2t + (4 * c0 + cc) * OO + g * KK;  // uniform
#pragma unroll
        for (int i = 0; i < WTAPS; ++i) {
          int kk = kk0 + i; kk = kk < KK ? kk : KK - 1;  // clamp (no OOB)
          acc[i] = fmaf(xv[cc], wr[kk], acc[i]);
        }
      }
    }
#pragma unroll
    for (int i = 0; i < WTAPS; ++i) {
      int kk = kk0 + i;
      if (kk < KK) wlds[kk * 64 + px] = acc[i];
    }
  }
  __syncthreads();

  // ---- phase 2: apply ----
  const int quad = tid & 15;                   // px quad: w0 = quad*4
  const int gc   = tid >> 4;                   // group channel 0..15
  const int w0   = quad * 4;

  float acc4[4] = {0.f, 0.f, 0.f, 0.f};
  const float* xp = x + ((size_t)b * C_IN + g * GC_ + gc) * HW;

#pragma unroll
  for (int kh = 0; kh < K_; ++kh) {
    const int y = row + kh - PAD_;
    if ((unsigned)y < (unsigned)H_) {          // wave-uniform branch
      const float* xr = xp + y * W_;
      float win[12];
      float4 zero4 = {0.f, 0.f, 0.f, 0.f};
      *(float4*)&win[0] = (w0 >= 4)  ? *(const float4*)(xr + w0 - 4) : zero4;
      *(float4*)&win[4] = *(const float4*)(xr + w0);
      *(float4*)&win[8] = (w0 <= 56) ? *(const float4*)(xr + w0 + 4) : zero4;
#pragma unroll
      for (int dw = 0; dw < 7; ++dw) {
        float wv[4];
        *(float4*)wv = *(const float4*)&wlds[(kh * 7 + dw) * 64 + w0];
#pragma unroll
        for (int cc = 0; cc < 4; ++cc)
          acc4[cc] = fmaf(wv[cc], win[cc + dw + 1], acc4[cc]);
      }
    }
  }

  float* ob = out + ((size_t)b * C_IN + g * GC_ + gc) * HW + row * W_ + w0;
  *(float4*)ob = *(float4*)acc4;
}

extern "C" void kernel_launch(void* const* d_in, const int* in_sizes, int n_in,
                              void* d_out, int out_size, void* d_ws, size_t ws_size,
                              hipStream_t stream) {
  const float* x     = (const float*)d_in[0];
  const float* w1    = (const float*)d_in[1];
  const float* b1    = (const float*)d_in[2];
  const float* gamma = (const float*)d_in[3];
  const float* beta  = (const float*)d_in[4];
  const float* mean  = (const float*)d_in[5];
  const float* var   = (const float*)d_in[6];
  const float* w2    = (const float*)d_in[7];
  const float* b2    = (const float*)d_in[8];
  float* out = (float*)d_out;
  const int B = in_sizes[0] / (C_IN * HW);

  // ws layout: [w1t 64KB][b1f][w2t 200KB][t B*1MB px-major]
  char* p = (char*)d_ws;
  float* w1t = (float*)p;  p += ((size_t)CR * C_IN * 4 + 255) & ~(size_t)255;
  float* b1f = (float*)p;  p += ((size_t)CR * 4 + 255) & ~(size_t)255;
  float* w2t = (float*)p;  p += ((size_t)OO * CR * 4 + 511) & ~(size_t)255;
  float* t   = (float*)p;

  prep_kernel<<<dim3((OO * CR + 255) / 256), 256, 0, stream>>>(
      w1, b1, gamma, beta, mean, var, w2, w1t, b1f, w2t);

  conv1_kernel<<<dim3(HW / 64, B), 1024, 0, stream>>>(x, w1t, b1f, t);

  conv2invol_kernel<<<dim3(H_ * G_ * B), 256, 0, stream>>>(x, t, w2t, b2, out);
}